// Round 17
// baseline (48.004 us; speedup 1.0000x reference)
//
#include <hip/hip_runtime.h>

#define T_SEQ 4096
#define NBATCH 2
#define DM 1024
#define DI 32
#define NH 4
#define NCOLS 164      // 128 q + 32 k + 4 w
#define NCOLS_PAD 192  // 12 tiles of 16
#define KC 64          // K-chunk
#define BSTRIDE 72     // shorts per col-slice in LDS (64 + 8 pad)

typedef __attribute__((ext_vector_type(8))) short bf16x8;
typedef __attribute__((ext_vector_type(4))) float f32x4;

__device__ __forceinline__ unsigned short f2bf(float f) {
    unsigned int u = __builtin_bit_cast(unsigned int, f);
    u += 0x7FFFu + ((u >> 16) & 1u);   // RNE; inputs have no NaN
    return (unsigned short)(u >> 16);
}

// ---------------- prep: W^T -> bf16 WT2[chunk][192 cols][64 k], bias[192] ----------------
// (bit-identical to R16)
__global__ __launch_bounds__(256) void prep_kernel(
    const float* __restrict__ Wq, const float* __restrict__ bq,
    const float* __restrict__ Wk, const float* __restrict__ bk,
    const float* __restrict__ Ww, const float* __restrict__ bw,
    unsigned short* __restrict__ WT2, float* __restrict__ bias) {
    int c = blockIdx.x;                    // col 0..191
    const float* src = nullptr; int stride = 0; float bv = 0.f;
    if (c < 128)      { src = Wq + c;       stride = NH * DI; bv = bq[c]; }
    else if (c < 160) { src = Wk + (c-128); stride = DI;      bv = bk[c-128]; }
    else if (c < 164) { src = Ww + (c-160); stride = NH;      bv = bw[c-160]; }
    for (int k = threadIdx.x; k < DM; k += blockDim.x) {
        float v = src ? src[(size_t)k * stride] : 0.f;
        WT2[((size_t)(k >> 6) * NCOLS_PAD + c) * KC + (k & 63)] = f2bf(v);
    }
    if (threadIdx.x == 0) bias[c] = bv;
}

// ---------------- projection v5: triple-buffer, 1 barrier/chunk (R16, best) ----------------
__global__ __launch_bounds__(512) void proj_kernel(
    const float* __restrict__ x, const unsigned short* __restrict__ WT2,
    const float* __restrict__ bias,
    unsigned short* __restrict__ qws, unsigned short* __restrict__ kws,
    float* __restrict__ wws) {
    __shared__ unsigned short Bb[3][NCOLS_PAD * BSTRIDE];  // 3 x 27648 B
    __shared__ unsigned short Ab[3][2048];                 // 3 x 4096 B
    int t = threadIdx.x;
    int wave = t >> 6, lane = t & 63;
    int lr = lane & 15, kg = lane >> 4;
    int r0 = blockIdx.x * 32;

    int ahalf = t & 1, alane = (t >> 1) & 63, akk = (t >> 7) & 1, arh = t >> 8;
    int arow = r0 + arh * 16 + (alane & 15);
    int tA = arow & (T_SEQ - 1), bA = arow >> 12;
    const float* xrowA = x + ((size_t)tA * NBATCH + bA) * DM;
    int aoff = akk * 32 + (alane >> 4) * 8 + ahalf * 4;
    int adst = arh * 1024 + akk * 512 + alane * 8 + ahalf * 4;

    bf16x8 bregA[3], bregB[3];
    f32x4  aregA, aregB;

    auto LOADA = [&](int c) {
        const unsigned short* wp = WT2 + (size_t)c * (NCOLS_PAD * KC);
        #pragma unroll
        for (int it = 0; it < 3; ++it)
            bregA[it] = *(const bf16x8*)(wp + (it * 512 + t) * 8);
        aregA = *(const f32x4*)(xrowA + c * KC + aoff);
    };
    auto LOADB = [&](int c) {
        const unsigned short* wp = WT2 + (size_t)c * (NCOLS_PAD * KC);
        #pragma unroll
        for (int it = 0; it < 3; ++it)
            bregB[it] = *(const bf16x8*)(wp + (it * 512 + t) * 8);
        aregB = *(const f32x4*)(xrowA + c * KC + aoff);
    };
    auto WRITEA = [&](int buf) {
        #pragma unroll
        for (int it = 0; it < 3; ++it) {
            int tau = it * 512 + t;
            *(bf16x8*)(&Bb[buf][(tau >> 3) * BSTRIDE + (tau & 7) * 8]) = bregA[it];
        }
        unsigned short* d = &Ab[buf][adst];
        d[0] = f2bf(aregA[0]); d[1] = f2bf(aregA[1]);
        d[2] = f2bf(aregA[2]); d[3] = f2bf(aregA[3]);
    };
    auto WRITEB = [&](int buf) {
        #pragma unroll
        for (int it = 0; it < 3; ++it) {
            int tau = it * 512 + t;
            *(bf16x8*)(&Bb[buf][(tau >> 3) * BSTRIDE + (tau & 7) * 8]) = bregB[it];
        }
        unsigned short* d = &Ab[buf][adst];
        d[0] = f2bf(aregB[0]); d[1] = f2bf(aregB[1]);
        d[2] = f2bf(aregB[2]); d[3] = f2bf(aregB[3]);
    };

    int ct0 = (wave >> 1) * 3;
    int rh  = wave & 1;
    f32x4 acc[3] = {};

    auto COMPUTE = [&](int buf) {
        #pragma unroll
        for (int kk = 0; kk < 2; ++kk) {
            bf16x8 af = *(const bf16x8*)(&Ab[buf][rh * 1024 + kk * 512 + lane * 8]);
            #pragma unroll
            for (int i = 0; i < 3; ++i) {
                int col = (ct0 + i) * 16 + lr;
                bf16x8 bfg = *(const bf16x8*)(&Bb[buf][col * BSTRIDE + kk * 32 + kg * 8]);
                acc[i] = __builtin_amdgcn_mfma_f32_16x16x32_bf16(af, bfg, acc[i], 0, 0, 0);
            }
        }
    };

    LOADA(0);
    WRITEA(0);
    LOADB(1);
    __syncthreads();

    int bc = 0;
    for (int c = 0; c < 16; c += 2) {
        int b1 = (bc + 1 == 3) ? 0 : bc + 1;
        int b2 = (b1 + 1 == 3) ? 0 : b1 + 1;
        if (c + 2 < 16) LOADA(c + 2);
        COMPUTE(bc);
        WRITEB(b1);
        __syncthreads();
        if (c + 3 < 16) LOADB(c + 3);
        COMPUTE(b1);
        if (c + 2 < 16) WRITEA(b2);
        __syncthreads();
        bc = b2;
    }

    #pragma unroll
    for (int i = 0; i < 3; ++i) {
        int cout = (ct0 + i) * 16 + lr;
        float bv = bias[cout];
        #pragma unroll
        for (int r = 0; r < 4; ++r) {
            int rr = r0 + rh * 16 + kg * 4 + r;
            int tt = rr & (T_SEQ - 1), bb = rr >> 12;
            float v = acc[i][r] + bv;
            size_t rowoff = (size_t)bb * T_SEQ + tt;
            if (cout < 128)       qws[rowoff * 128 + cout] = f2bf(v);
            else if (cout < 160)  kws[rowoff * 32 + (cout - 128)] = f2bf(v);
            else if (cout < 164)  wws[rowoff * 4 + (cout - 160)] = v;
        }
    }
}

// ---------------- indexer v5: single scheduling round, 2 t-groups/block ----------------
// 1024 blocks x 512 thr = 4 blocks/CU -> ALL blocks co-resident (one round,
// no inter-round drain skew). Block = (b, t64-group, 512-s slab): stages the
// 32 KB k-slab ONCE, reuses it for two 32-row t-groups (k L2 reads 64->32 MB).
// Per-group compute/store body bit-identical to R15/R16.
__global__ __launch_bounds__(512) void indexer_kernel(
    const unsigned short* __restrict__ qws, const unsigned short* __restrict__ kws,
    const float* __restrict__ wws, float* __restrict__ out) {
    __shared__ unsigned short kf_lds[16384];   // 32 tiles x 64 lanes x 8 bf16
    int t = threadIdx.x;
    int wave = t >> 6;
    int lane = t & 63;
    int lr = lane & 15, kg = lane >> 4;

    int blk = blockIdx.x;                  // 0..1023
    int b = blk >> 9;
    int rem = blk & 511;
    int t64 = rem >> 3;                    // 0..63
    int sblk = rem & 7;                    // 0..7
    int s0 = sblk * 512;

    const unsigned short* kbase = kws + (size_t)b * T_SEQ * 32;

    // stage k slab once (fragment-linear layout, coalesced reads)
    {
        const unsigned short* krow = kbase + (size_t)(s0 + t) * 32;
        int ldst = (t >> 4) * 512 + (t & 15) * 8;
        #pragma unroll
        for (int j = 0; j < 4; ++j) {
            bf16x8 kv = *(const bf16x8*)(krow + j * 8);
            *(bf16x8*)(&kf_lds[ldst + j * 128]) = kv;
        }
    }

    int h = wave & 1;                      // t-half within 32-row group
    int sq = wave >> 1;                    // s-quarter (0..3)
    __syncthreads();

    #pragma unroll
    for (int tg = 0; tg < 2; ++tg) {
        int trow = t64 * 64 + tg * 32 + h * 16;

        const unsigned short* qrow = qws + ((size_t)b * T_SEQ + trow + lr) * 128;
        bf16x8 qf[4];
        #pragma unroll
        for (int hh = 0; hh < 4; ++hh)
            qf[hh] = *(const bf16x8*)(qrow + hh * 32 + kg * 8);

        f32x4 w4 = *(const f32x4*)(wws + ((size_t)b * T_SEQ + trow + lr) * 4);

        float* outrow = out + (size_t)b * T_SEQ * T_SEQ + (size_t)(trow + lr) * T_SEQ
                      + s0 + sq * 128;

        #pragma unroll 2
        for (int st = 0; st < 8; ++st) {
            int sl = sq * 8 + st;
            bf16x8 kf = *(const bf16x8*)(&kf_lds[sl * 512 + lane * 8]);
            f32x4 z = {0.f, 0.f, 0.f, 0.f};
            f32x4 a0 = __builtin_amdgcn_mfma_f32_16x16x32_bf16(kf, qf[0], z, 0, 0, 0);
            f32x4 a1 = __builtin_amdgcn_mfma_f32_16x16x32_bf16(kf, qf[1], z, 0, 0, 0);
            f32x4 a2 = __builtin_amdgcn_mfma_f32_16x16x32_bf16(kf, qf[2], z, 0, 0, 0);
            f32x4 a3 = __builtin_amdgcn_mfma_f32_16x16x32_bf16(kf, qf[3], z, 0, 0, 0);
            f32x4 v;
            #pragma unroll
            for (int r = 0; r < 4; ++r) {
                v[r] = fmaxf(a0[r], 0.f) * w4[0] + fmaxf(a1[r], 0.f) * w4[1]
                     + fmaxf(a2[r], 0.f) * w4[2] + fmaxf(a3[r], 0.f) * w4[3];
            }
            *(f32x4*)(outrow + st * 16 + kg * 4) = v;
        }
    }
}

extern "C" void kernel_launch(void* const* d_in, const int* in_sizes, int n_in,
                              void* d_out, int out_size, void* d_ws, size_t ws_size,
                              hipStream_t stream) {
    const float* x  = (const float*)d_in[0];
    const float* Wq = (const float*)d_in[1];
    const float* bq = (const float*)d_in[2];
    const float* Wk = (const float*)d_in[3];
    const float* bk = (const float*)d_in[4];
    const float* Ww = (const float*)d_in[5];
    const float* bw = (const float*)d_in[6];
    float* out = (float*)d_out;

    char* ws = (char*)d_ws;
    unsigned short* WT2 = (unsigned short*)(ws);            // 16*192*64*2 = 393216 B
    float* bias         = (float*)(ws + 393216);            // 768 B
    unsigned short* qws = (unsigned short*)(ws + 524288);   // 2 MB
    unsigned short* kws = (unsigned short*)(ws + 2621440);  // 512 KB
    float* wws          = (float*)(ws + 3145728);           // 128 KB

    prep_kernel<<<dim3(NCOLS_PAD), dim3(256), 0, stream>>>(Wq, bq, Wk, bk, Ww, bw, WT2, bias);
    proj_kernel<<<dim3(256), dim3(512), 0, stream>>>(x, WT2, bias, qws, kws, wws);
    indexer_kernel<<<dim3(1024), dim3(512), 0, stream>>>(qws, kws, wws, out);
}